// Round 1
// baseline (38.837 us; speedup 1.0000x reference)
//
#include <hip/hip_runtime.h>
#include <math.h>

// Duhamel layer == per-channel causal FIR with h[q] = (1/wD) r^q sin(q*theta).
// Computed exactly as y[n] = Im(z1[n]) - Im(g^W * z2[n]) where
//   z1[n] = g z1[n-1] + (1/wD) x[n]        (first-order complex IIR)
//   z2[n] = g z2[n-1] + (1/wD) x[n-W]      (same IIR on W-delayed input)
// Chunked with redundant halo + intra-block affine scan (no cross-block deps).

#define N_SAMP  65536
#define NB      16
#define NO      8
#define L_OUT   4096
#define HALO    4096
#define T_SPAN  (L_OUT + HALO)      // 8192
#define NTHREADS 256
#define LSEG    (T_SPAN / NTHREADS) // 32
#define WPAD    1848                // >= max W (1844), multiple of 8
#define XW      (T_SPAN + WPAD)     // 10040 staged floats
#define CCHUNK  (N_SAMP / L_OUT)    // 16
#define OUT_T0  (HALO / LSEG)       // 128

struct DuhParams { int W[NO]; };

__device__ __forceinline__ int pidx(int i) { return i + (i >> 5); }  // +1 pad per 32 floats

__global__ __launch_bounds__(NTHREADS)
void duhamel_iir_kernel(const float* __restrict__ x,
                        const float* __restrict__ logw,
                        float* __restrict__ out,
                        DuhParams P)
{
    __shared__ float lds_x[XW + (XW >> 5) + 2];
    __shared__ float lds_y[L_OUT + (L_OUT >> 5) + 2];
    __shared__ float wtot[4][4];

    const int bid = blockIdx.x;
    const int o   = bid & (NO - 1);
    const int bc  = bid >> 3;
    const int c   = bc & (CCHUNK - 1);
    const int b   = bc >> 4;            // CCHUNK == 16
    const int n0  = c * L_OUT;
    const int t   = threadIdx.x;
    const int lane = t & 63;
    const int wv   = t >> 6;

    // ---------------- per-channel constants (f32) ----------------
    const float XIf = 0.05f, DTf = 0.01f;
    const float omf  = fminf(fmaxf(expf(logw[o]), 0.01f), 1000.0f);
    const float sqf  = sqrtf(1.0f - XIf * XIf);
    const float omD  = omf * sqf;
    const float th   = omD * DTf;          // per-step phase
    const float alph = XIf * omf * DTf;    // per-step log-decay
    const float binv = 1.0f / omD;
    const int   W    = P.W[o];

    float sn, cn;
    const float r1 = expf(-alph);
    sincosf(th, &sn, &cn);
    const float gr  = r1 * cn, gi_ = r1 * sn;          // g

    const float rW = expf(-alph * (float)W);
    sincosf(th * (float)W, &sn, &cn);
    const float gWr = rW * cn, gWi = rW * sn;          // g^W

    float Mr[7], Mi[7];                                 // M[k] = g^(LSEG*2^k)
    {
        const float rl = expf(-alph * (float)LSEG);
        sincosf(th * (float)LSEG, &sn, &cn);
        float pr = rl * cn, pi_ = rl * sn;
        for (int k = 0; k < 7; ++k) {
            Mr[k] = pr; Mi[k] = pi_;
            const float nr2 = pr * pr - pi_ * pi_;
            const float ni2 = 2.0f * pr * pi_;
            pr = nr2; pi_ = ni2;
        }
    }

    // ---------------- stage x window into LDS (padded) ----------------
    const int xbase = n0 - HALO - WPAD;                 // global idx of lds_x[0]
    const float* xb = x + (size_t)b * N_SAMP;
    for (int k = 4 * t; k < XW; k += 4 * NTHREADS) {
        const int g0 = xbase + k;                       // g0+3 < N_SAMP always
        float4 v;
        if (g0 >= 0) {
            v = *(const float4*)(xb + g0);
        } else {
            v.x = (g0 + 0 >= 0) ? xb[g0 + 0] : 0.0f;
            v.y = (g0 + 1 >= 0) ? xb[g0 + 1] : 0.0f;
            v.z = (g0 + 2 >= 0) ? xb[g0 + 2] : 0.0f;
            v.w = (g0 + 3 >= 0) ? xb[g0 + 3] : 0.0f;
        }
        const int p = pidx(k);                          // k..k+3 stay in one 32-block
        lds_x[p] = v.x; lds_x[p + 1] = v.y; lds_x[p + 2] = v.z; lds_x[p + 3] = v.w;
    }
    __syncthreads();

    // ---------------- phase A: zero-init local scans ----------------
    const int b1 = WPAD + t * LSEG;   // stream 1: x[n]
    const int b2 = b1 - W;            // stream 2: x[n-W]  (b2 >= 4)
    float z1r = 0.f, z1i = 0.f, z2r = 0.f, z2i = 0.f;
#pragma unroll
    for (int j = 0; j < LSEG; ++j) {
        const float xa  = lds_x[pidx(b1 + j)];
        const float xb2 = lds_x[pidx(b2 + j)];
        const float n1r = fmaf(gr, z1r, fmaf(-gi_, z1i, binv * xa));
        const float n1i = fmaf(gi_, z1r, gr * z1i);
        z1r = n1r; z1i = n1i;
        const float n2r = fmaf(gr, z2r, fmaf(-gi_, z2i, binv * xb2));
        const float n2i = fmaf(gi_, z2r, gr * z2i);
        z2r = n2r; z2i = n2i;
    }

    // ---------------- wave-level inclusive affine scan ----------------
    float S1r = z1r, S1i = z1i, S2r = z2r, S2i = z2i;
#pragma unroll
    for (int k = 0; k < 6; ++k) {
        const int d = 1 << k;
        const float u1r = __shfl_up(S1r, d, 64);
        const float u1i = __shfl_up(S1i, d, 64);
        const float u2r = __shfl_up(S2r, d, 64);
        const float u2i = __shfl_up(S2i, d, 64);
        if (lane >= d) {
            const float a1r = fmaf(Mr[k], u1r, fmaf(-Mi[k], u1i, S1r));
            const float a1i = fmaf(Mr[k], u1i, fmaf( Mi[k], u1r, S1i));
            const float a2r = fmaf(Mr[k], u2r, fmaf(-Mi[k], u2i, S2r));
            const float a2i = fmaf(Mr[k], u2i, fmaf( Mi[k], u2r, S2i));
            S1r = a1r; S1i = a1i; S2r = a2r; S2i = a2i;
        }
    }
    if (lane == 63) {
        wtot[wv][0] = S1r; wtot[wv][1] = S1i; wtot[wv][2] = S2r; wtot[wv][3] = S2i;
    }
    __syncthreads();

    // cross-wave carries (state entering this wave)
    float c1r = 0.f, c1i = 0.f, c2r = 0.f, c2i = 0.f;
    for (int w2 = 0; w2 < wv; ++w2) {
        const float t1r = wtot[w2][0], t1i = wtot[w2][1];
        const float t2r = wtot[w2][2], t2i = wtot[w2][3];
        const float nc1r = fmaf(Mr[6], c1r, fmaf(-Mi[6], c1i, t1r));
        const float nc1i = fmaf(Mr[6], c1i, fmaf( Mi[6], c1r, t1i));
        const float nc2r = fmaf(Mr[6], c2r, fmaf(-Mi[6], c2i, t2r));
        const float nc2i = fmaf(Mr[6], c2i, fmaf( Mi[6], c2r, t2i));
        c1r = nc1r; c1i = nc1i; c2r = nc2r; c2i = nc2i;
    }

    // exclusive in-wave prefix
    float p1r = __shfl_up(S1r, 1, 64);
    float p1i = __shfl_up(S1i, 1, 64);
    float p2r = __shfl_up(S2r, 1, 64);
    float p2i = __shfl_up(S2i, 1, 64);
    if (lane == 0) { p1r = p1i = p2r = p2i = 0.f; }

    // m^lane (product over set bits)
    float plr = 1.f, pli = 0.f;
#pragma unroll
    for (int k = 0; k < 6; ++k) {
        if ((lane >> k) & 1) {
            const float nr2 = plr * Mr[k] - pli * Mi[k];
            const float ni2 = plr * Mi[k] + pli * Mr[k];
            plr = nr2; pli = ni2;
        }
    }
    // state entering this thread's segment: p + m^lane * wave_carry
    z1r = fmaf(plr, c1r, fmaf(-pli, c1i, p1r));
    z1i = fmaf(plr, c1i, fmaf( pli, c1r, p1i));
    z2r = fmaf(plr, c2r, fmaf(-pli, c2i, p2r));
    z2i = fmaf(plr, c2i, fmaf( pli, c2r, p2i));

    // ---------------- phase B: re-scan with carries, emit y ----------------
    if (t >= OUT_T0) {
        const int ybase = (t - OUT_T0) * LSEG;
#pragma unroll
        for (int j = 0; j < LSEG; ++j) {
            const float xa  = lds_x[pidx(b1 + j)];
            const float xb2 = lds_x[pidx(b2 + j)];
            const float n1r = fmaf(gr, z1r, fmaf(-gi_, z1i, binv * xa));
            const float n1i = fmaf(gi_, z1r, gr * z1i);
            z1r = n1r; z1i = n1i;
            const float n2r = fmaf(gr, z2r, fmaf(-gi_, z2i, binv * xb2));
            const float n2i = fmaf(gi_, z2r, gr * z2i);
            z2r = n2r; z2i = n2i;
            const float y = z1i - fmaf(gWr, z2i, gWi * z2r);  // Im(z1) - Im(g^W z2)
            lds_y[pidx(ybase + j)] = y;
        }
    }
    __syncthreads();

    // ---------------- coalesced writeout ----------------
    float* ob = out + ((size_t)(b * NO + o)) * (size_t)N_SAMP + n0;
    for (int k = 4 * t; k < L_OUT; k += 4 * NTHREADS) {
        const int p = pidx(k);
        float4 v;
        v.x = lds_y[p]; v.y = lds_y[p + 1]; v.z = lds_y[p + 2]; v.w = lds_y[p + 3];
        *(float4*)(ob + k) = v;
    }
}

extern "C" void kernel_launch(void* const* d_in, const int* in_sizes, int n_in,
                              void* d_out, int out_size, void* d_ws, size_t ws_size,
                              hipStream_t stream) {
    const float* x  = (const float*)d_in[0];
    const float* lw = (const float*)d_in[1];
    float* out = (float*)d_out;

    // Exact double-precision replica of the numpy VALID_W computation
    // (depends only on the static OMEGAS, not on the log_omegas input).
    DuhParams P;
    const double OM[NO] = {5.0, 7.0, 9.0, 12.0, 16.0, 22.0, 30.0, 40.0};
    const double xi = 0.05, dt = 0.01, uj = 0.01;
    const double decay = (1.0 / (2.0 * M_PI * xi)) * log(1.0 / uj);
    const double sq = sqrt(1.0 - xi * xi);
    for (int i = 0; i < NO; ++i)
        P.W[i] = (int)(2.0 * M_PI / OM[i] / sq * decay / dt);

    dim3 grid(NB * NO * CCHUNK);   // 2048 blocks
    dim3 block(NTHREADS);
    duhamel_iir_kernel<<<grid, block, 0, stream>>>(x, lw, out, P);
}

// Round 2
// 28.936 us; speedup vs baseline: 1.3421x; 1.3421x over previous
//
#include <hip/hip_runtime.h>
#include <math.h>

// Duhamel layer == per-channel causal FIR with h[q] = (1/wD) r^q sin(q*theta).
// y[n] = Im(z1[n]) - Im(g^W * z2[n]),  z = g*z + (1/wD)*x (complex IIR),
// stream2 = same IIR on x delayed by W.  Chunked with per-channel halo +
// intra-block affine (Hillis-Steele) scan; no cross-block dependencies.

#define N_SAMP  65536
#define NB      16
#define NO      8
#define SPAN    8192                 // samples scanned per block (halo + out)
#define NTHREADS 256
#define LSEG    32                   // SPAN / NTHREADS
#define MAXWPAD 1856                 // max W (1844) rounded up to 32
#define MAXXW   (SPAN + MAXWPAD)     // 10048
#define LDSX    (MAXXW + (MAXXW >> 5) + 4)

struct DuhParams {
    int W[NO];        // exact FIR length (delay of stream 2)
    int Wpad[NO];     // W rounded up to mult of 32 (staging offset)
    int H[NO];        // per-channel halo, mult of 32
    int L[NO];        // SPAN - H = outputs per block
    int coff[NO + 1]; // cumulative chunk counts per channel
};

__device__ __forceinline__ int pidx(int i) { return i + (i >> 5); }  // +1 pad / 32 floats

__global__ __launch_bounds__(NTHREADS)
void duhamel_iir_kernel(const float* __restrict__ x,
                        const float* __restrict__ logw,
                        float* __restrict__ out,
                        DuhParams P)
{
    __shared__ float lds_x[LDSX];
    __shared__ float wtot[4][4];

    const int cid = blockIdx.x;
    const int b   = blockIdx.y;
    int o = 0;
#pragma unroll
    for (int q = 1; q < NO; ++q) o += (cid >= P.coff[q]) ? 1 : 0;
    const int c     = cid - P.coff[o];
    const int W     = P.W[o];
    const int Wpad  = P.Wpad[o];
    const int H     = P.H[o];
    const int L     = P.L[o];
    const int n0    = c * L;
    const int OUT_T0 = H >> 5;
    const int XW    = SPAN + Wpad;

    const int t    = threadIdx.x;
    const int lane = t & 63;
    const int wv   = t >> 6;

    // ---------------- per-channel constants (f32) ----------------
    const float XIf = 0.05f, DTf = 0.01f;
    const float omf  = fminf(fmaxf(expf(logw[o]), 0.01f), 1000.0f);
    const float sqf  = sqrtf(1.0f - XIf * XIf);
    const float omD  = omf * sqf;
    const float th   = omD * DTf;
    const float alph = XIf * omf * DTf;
    const float binv = 1.0f / omD;

    float sn, cn;
    const float r1 = expf(-alph);
    sincosf(th, &sn, &cn);
    const float gr  = r1 * cn, gi_ = r1 * sn;           // g

    const float rW = expf(-alph * (float)W);
    sincosf(th * (float)W, &sn, &cn);
    const float gWr = rW * cn, gWi = rW * sn;           // g^W

    float Mr[7], Mi[7];                                  // M[k] = g^(32*2^k)
    {
        const float rl = expf(-alph * (float)LSEG);
        sincosf(th * (float)LSEG, &sn, &cn);
        float pr = rl * cn, pi_ = rl * sn;
        for (int k = 0; k < 7; ++k) {
            Mr[k] = pr; Mi[k] = pi_;
            const float nr2 = pr * pr - pi_ * pi_;
            const float ni2 = 2.0f * pr * pi_;
            pr = nr2; pi_ = ni2;
        }
    }

    // ---------------- stage binv*x window into LDS (padded) ----------------
    const int xbase = n0 - H - Wpad;                     // global idx of lds_x[0]
    const float* xb = x + (size_t)b * N_SAMP;
    for (int k = 4 * t; k < XW; k += 4 * NTHREADS) {
        const int g0 = xbase + k;
        float4 v;
        if (g0 >= 0 && g0 + 3 < N_SAMP) {
            v = *(const float4*)(xb + g0);
        } else {
            v.x = (g0 + 0 >= 0 && g0 + 0 < N_SAMP) ? xb[g0 + 0] : 0.0f;
            v.y = (g0 + 1 >= 0 && g0 + 1 < N_SAMP) ? xb[g0 + 1] : 0.0f;
            v.z = (g0 + 2 >= 0 && g0 + 2 < N_SAMP) ? xb[g0 + 2] : 0.0f;
            v.w = (g0 + 3 >= 0 && g0 + 3 < N_SAMP) ? xb[g0 + 3] : 0.0f;
        }
        const int p = pidx(k);
        lds_x[p]     = binv * v.x;
        lds_x[p + 1] = binv * v.y;
        lds_x[p + 2] = binv * v.z;
        lds_x[p + 3] = binv * v.w;
    }
    __syncthreads();

    // ---------------- phase A: zero-init local scans ----------------
    const int b1  = Wpad + (t << 5);        // mult of 32
    const int pb1 = pidx(b1);               // => pidx(b1+j) = pb1 + j for j<32
    const int b2  = b1 - W;                 // >= 0
    const int pb2 = pidx(b2);
    const int j0  = 32 - (b2 & 31);         // j >= j0 crosses one pad boundary

    float z1r = 0.f, z1i = 0.f, z2r = 0.f, z2i = 0.f;
#pragma unroll
    for (int j = 0; j < LSEG; ++j) {
        const float xa  = lds_x[pb1 + j];
        const float xc  = lds_x[pb2 + j + ((j >= j0) ? 1 : 0)];
        const float n1r = fmaf(gr, z1r, fmaf(-gi_, z1i, xa));
        const float n1i = fmaf(gi_, z1r, gr * z1i);
        z1r = n1r; z1i = n1i;
        const float n2r = fmaf(gr, z2r, fmaf(-gi_, z2i, xc));
        const float n2i = fmaf(gi_, z2r, gr * z2i);
        z2r = n2r; z2i = n2i;
    }

    // ---------------- wave-level inclusive affine scan ----------------
    float S1r = z1r, S1i = z1i, S2r = z2r, S2i = z2i;
#pragma unroll
    for (int k = 0; k < 6; ++k) {
        const int d = 1 << k;
        const float u1r = __shfl_up(S1r, d, 64);
        const float u1i = __shfl_up(S1i, d, 64);
        const float u2r = __shfl_up(S2r, d, 64);
        const float u2i = __shfl_up(S2i, d, 64);
        if (lane >= d) {
            const float a1r = fmaf(Mr[k], u1r, fmaf(-Mi[k], u1i, S1r));
            const float a1i = fmaf(Mr[k], u1i, fmaf( Mi[k], u1r, S1i));
            const float a2r = fmaf(Mr[k], u2r, fmaf(-Mi[k], u2i, S2r));
            const float a2i = fmaf(Mr[k], u2i, fmaf( Mi[k], u2r, S2i));
            S1r = a1r; S1i = a1i; S2r = a2r; S2i = a2i;
        }
    }
    if (lane == 63) {
        wtot[wv][0] = S1r; wtot[wv][1] = S1i; wtot[wv][2] = S2r; wtot[wv][3] = S2i;
    }
    __syncthreads();

    // cross-wave carries (state entering this wave), multiplier g^2048 = M[6]
    float c1r = 0.f, c1i = 0.f, c2r = 0.f, c2i = 0.f;
    for (int w2 = 0; w2 < wv; ++w2) {
        const float t1r = wtot[w2][0], t1i = wtot[w2][1];
        const float t2r = wtot[w2][2], t2i = wtot[w2][3];
        const float nc1r = fmaf(Mr[6], c1r, fmaf(-Mi[6], c1i, t1r));
        const float nc1i = fmaf(Mr[6], c1i, fmaf( Mi[6], c1r, t1i));
        const float nc2r = fmaf(Mr[6], c2r, fmaf(-Mi[6], c2i, t2r));
        const float nc2i = fmaf(Mr[6], c2i, fmaf( Mi[6], c2r, t2i));
        c1r = nc1r; c1i = nc1i; c2r = nc2r; c2i = nc2i;
    }

    // exclusive in-wave prefix
    float p1r = __shfl_up(S1r, 1, 64);
    float p1i = __shfl_up(S1i, 1, 64);
    float p2r = __shfl_up(S2r, 1, 64);
    float p2i = __shfl_up(S2i, 1, 64);
    if (lane == 0) { p1r = p1i = p2r = p2i = 0.f; }

    // m^lane (product over set bits of lane)
    float plr = 1.f, pli = 0.f;
#pragma unroll
    for (int k = 0; k < 6; ++k) {
        if ((lane >> k) & 1) {
            const float nr2 = plr * Mr[k] - pli * Mi[k];
            const float ni2 = plr * Mi[k] + pli * Mr[k];
            plr = nr2; pli = ni2;
        }
    }
    // state entering this thread's segment
    z1r = fmaf(plr, c1r, fmaf(-pli, c1i, p1r));
    z1i = fmaf(plr, c1i, fmaf( pli, c1r, p1i));
    z2r = fmaf(plr, c2r, fmaf(-pli, c2i, p2r));
    z2i = fmaf(plr, c2i, fmaf( pli, c2r, p2i));

    // ---------------- phase B: re-scan with carries, store direct ----------------
    const int tO   = t - OUT_T0;
    const int nout = n0 + (tO << 5);
    if (t >= OUT_T0 && nout < N_SAMP) {     // nout, N both mult of 32 -> whole seg valid
        float* op = out + ((size_t)(b * NO + o)) * (size_t)N_SAMP + nout;
#pragma unroll
        for (int jq = 0; jq < 8; ++jq) {
            float4 yv;
#pragma unroll
            for (int u = 0; u < 4; ++u) {
                const int j = jq * 4 + u;
                const float xa  = lds_x[pb1 + j];
                const float xc  = lds_x[pb2 + j + ((j >= j0) ? 1 : 0)];
                const float n1r = fmaf(gr, z1r, fmaf(-gi_, z1i, xa));
                const float n1i = fmaf(gi_, z1r, gr * z1i);
                z1r = n1r; z1i = n1i;
                const float n2r = fmaf(gr, z2r, fmaf(-gi_, z2i, xc));
                const float n2i = fmaf(gi_, z2r, gr * z2i);
                z2r = n2r; z2i = n2i;
                const float y = z1i - fmaf(gWr, z2i, gWi * z2r);
                ((float*)&yv)[u] = y;
            }
            *(float4*)(op + jq * 4) = yv;
        }
    }
}

extern "C" void kernel_launch(void* const* d_in, const int* in_sizes, int n_in,
                              void* d_out, int out_size, void* d_ws, size_t ws_size,
                              hipStream_t stream) {
    const float* x  = (const float*)d_in[0];
    const float* lw = (const float*)d_in[1];
    float* out = (float*)d_out;

    // Exact double-precision replica of the numpy VALID_W computation
    // (depends only on the static OMEGAS, not on the log_omegas input).
    DuhParams P;
    const double OM[NO] = {5.0, 7.0, 9.0, 12.0, 16.0, 22.0, 30.0, 40.0};
    const double xi = 0.05, dt = 0.01, uj = 0.01;
    const double decay = (1.0 / (2.0 * M_PI * xi)) * log(1.0 / uj);
    const double sq = sqrt(1.0 - xi * xi);
    int total = 0;
    for (int i = 0; i < NO; ++i) {
        P.W[i]    = (int)(2.0 * M_PI / OM[i] / sq * decay / dt);
        P.Wpad[i] = (P.W[i] + 31) & ~31;
        const double alpha = xi * OM[i] * dt;           // per-step log decay
        int h = (int)ceil(9.5 / alpha);                 // e^-9.5 ~ 7.5e-5 seed error
        h = (h + 31) & ~31;
        P.H[i] = h;
        P.L[i] = SPAN - h;
        P.coff[i] = total;
        total += (N_SAMP + P.L[i] - 1) / P.L[i];
    }
    P.coff[NO] = total;   // 85 chunks

    dim3 grid(total, NB); // 85 x 16 = 1360 blocks
    duhamel_iir_kernel<<<grid, dim3(NTHREADS), 0, stream>>>(x, lw, out, P);
}

// Round 3
// 26.340 us; speedup vs baseline: 1.4744x; 1.0986x over previous
//
#include <hip/hip_runtime.h>
#include <math.h>

// Duhamel layer == per-channel causal FIR with h[q] = (1/wD) r^q sin(q*theta).
// y[n] = Im(z1[n]) - Im(g^W * z2[n]);  z = g*z + (1/wD)*x  (complex IIR);
// stream2 = same IIR on x delayed by W.  Per-channel COMPILE-TIME W/H/L:
// all LDS reads become aligned ds_read_b128 quads with static shifts.
// Chunked with per-channel halo + intra-block affine scan (512 thr, LSEG=16).

#define N_SAMP  65536
#define NB      16
#define NO      8
#define SPAN    8192
#define NT      512
#define LSEG    16

// Static FIR lengths (exact replica of reference VALID_W, values verified):
constexpr int CW[NO]  = {1844, 1317, 1024, 768, 576, 419, 307, 230};
// Halo: ceil(7/alpha) rounded up to 32 (seed error e^-7 ~ 9e-4 relative).
constexpr int CHH[NO] = {2816, 2016, 1568, 1184, 896, 640, 480, 352};
// chunk counts: ceil(65536/(8192-H)) = {13,11,10,10,9,9,9,9}, prefix 80.

// +4 floats of pad per 32 (keeps 16B alignment of every 4-aligned logical idx)
__device__ __forceinline__ int pidx4(int i) { return i + ((i >> 5) << 2); }

template<int O>
__device__ __forceinline__ void duh_run(const float* __restrict__ xg,
                                        const float* __restrict__ logw,
                                        float* __restrict__ out,
                                        float* __restrict__ lds_x,
                                        float (* __restrict__ wtot)[4],
                                        int c, int b)
{
    constexpr int W    = CW[O];
    constexpr int Wpad = (W + 31) & ~31;
    constexpr int H    = CHH[O];
    constexpr int L    = SPAN - H;
    constexpr int XW   = SPAN + Wpad;
    constexpr int OUT_T0 = H / LSEG;
    constexpr int E    = Wpad - W;          // 0..31, static
    constexpr int D    = E & 3;             // quad mis-shift, static
    constexpr int NQ2  = (D == 0) ? 4 : 5;  // stream-2 quads per 16 samples

    const int n0   = c * L;
    const int t    = threadIdx.x;
    const int lane = t & 63;
    const int wv   = t >> 6;

    // ---------------- per-channel constants (f32, from runtime logw) --------
    const float XIf = 0.05f, DTf = 0.01f;
    const float omf  = fminf(fmaxf(expf(logw[O]), 0.01f), 1000.0f);
    const float sqf  = sqrtf(1.0f - XIf * XIf);
    const float omD  = omf * sqf;
    const float th   = omD * DTf;
    const float alph = XIf * omf * DTf;
    const float binv = 1.0f / omD;

    float sn, cn;
    const float r1 = expf(-alph);
    sincosf(th, &sn, &cn);
    const float gr = r1 * cn, gi_ = r1 * sn;            // g

    const float rW = expf(-alph * (float)W);
    sincosf(th * (float)W, &sn, &cn);
    const float gWr = rW * cn, gWi = rW * sn;           // g^W

    float Mr[7], Mi[7];                                  // M[k] = g^(16*2^k)
    {
        const float rl = expf(-alph * (float)LSEG);
        sincosf(th * (float)LSEG, &sn, &cn);
        float pr = rl * cn, pi_ = rl * sn;
#pragma unroll
        for (int k = 0; k < 7; ++k) {
            Mr[k] = pr; Mi[k] = pi_;
            const float nr2 = pr * pr - pi_ * pi_;
            const float ni2 = 2.0f * pr * pi_;
            pr = nr2; pi_ = ni2;
        }
    }

    // ---------------- stage binv*x window into LDS (quad-padded) ------------
    const int xbase = n0 - H - Wpad;                     // global idx of lds_x[0]
    const float* xb = xg + (size_t)b * N_SAMP;
#pragma unroll 2
    for (int k = 4 * t; k < XW; k += 4 * NT) {
        const int g0 = xbase + k;
        float4 v;
        if (g0 >= 0 && g0 + 3 < N_SAMP) {
            v = *(const float4*)(xb + g0);
        } else {
            v.x = (g0 + 0 >= 0 && g0 + 0 < N_SAMP) ? xb[g0 + 0] : 0.0f;
            v.y = (g0 + 1 >= 0 && g0 + 1 < N_SAMP) ? xb[g0 + 1] : 0.0f;
            v.z = (g0 + 2 >= 0 && g0 + 2 < N_SAMP) ? xb[g0 + 2] : 0.0f;
            v.w = (g0 + 3 >= 0 && g0 + 3 < N_SAMP) ? xb[g0 + 3] : 0.0f;
        }
        v.x *= binv; v.y *= binv; v.z *= binv; v.w *= binv;
        *(float4*)&lds_x[pidx4(k)] = v;
    }
    __syncthreads();

    const int b1 = Wpad + (t << 4);          // stream-1 base (mult of 16)
    const int a2 = b1 - W - D;               // stream-2 aligned quad base (mult 4)

    // quad loads -> static-indexed sample arrays (all reg, no scratch)
    float sa[LSEG], sc[LSEG];
#define LOAD_STREAMS()                                                        \
    {                                                                         \
        _Pragma("unroll")                                                     \
        for (int m = 0; m < 4; ++m) {                                         \
            const float4 q = *(const float4*)&lds_x[pidx4(b1 + 4 * m)];       \
            sa[4*m] = q.x; sa[4*m+1] = q.y; sa[4*m+2] = q.z; sa[4*m+3] = q.w; \
        }                                                                     \
        _Pragma("unroll")                                                     \
        for (int m = 0; m < NQ2; ++m) {                                       \
            const float4 q = *(const float4*)&lds_x[pidx4(a2 + 4 * m)];       \
            _Pragma("unroll")                                                 \
            for (int u = 0; u < 4; ++u) {                                     \
                const int idx = 4 * m + u - D;                                \
                if (idx >= 0 && idx < LSEG)                                   \
                    sc[idx] = (u == 0) ? q.x : (u == 1) ? q.y                 \
                                       : (u == 2) ? q.z : q.w;                \
            }                                                                 \
        }                                                                     \
    }

    // ---------------- phase A: zero-init local scans ------------------------
    float z1r = 0.f, z1i = 0.f, z2r = 0.f, z2i = 0.f;
    LOAD_STREAMS();
#pragma unroll
    for (int j = 0; j < LSEG; ++j) {
        const float n1r = fmaf(gr, z1r, fmaf(-gi_, z1i, sa[j]));
        const float n1i = fmaf(gi_, z1r, gr * z1i);
        z1r = n1r; z1i = n1i;
        const float n2r = fmaf(gr, z2r, fmaf(-gi_, z2i, sc[j]));
        const float n2i = fmaf(gi_, z2r, gr * z2i);
        z2r = n2r; z2i = n2i;
    }

    // ---------------- wave-level inclusive affine scan ----------------------
    float S1r = z1r, S1i = z1i, S2r = z2r, S2i = z2i;
#pragma unroll
    for (int k = 0; k < 6; ++k) {
        const int d = 1 << k;
        const float u1r = __shfl_up(S1r, d, 64);
        const float u1i = __shfl_up(S1i, d, 64);
        const float u2r = __shfl_up(S2r, d, 64);
        const float u2i = __shfl_up(S2i, d, 64);
        if (lane >= d) {
            const float a1r = fmaf(Mr[k], u1r, fmaf(-Mi[k], u1i, S1r));
            const float a1i = fmaf(Mr[k], u1i, fmaf( Mi[k], u1r, S1i));
            const float a2r = fmaf(Mr[k], u2r, fmaf(-Mi[k], u2i, S2r));
            const float a2i = fmaf(Mr[k], u2i, fmaf( Mi[k], u2r, S2i));
            S1r = a1r; S1i = a1i; S2r = a2r; S2i = a2i;
        }
    }
    if (lane == 63) {
        wtot[wv][0] = S1r; wtot[wv][1] = S1i; wtot[wv][2] = S2r; wtot[wv][3] = S2i;
    }
    __syncthreads();

    // cross-wave carries (multiplier g^1024 = M[6])
    float c1r = 0.f, c1i = 0.f, c2r = 0.f, c2i = 0.f;
    for (int w2 = 0; w2 < wv; ++w2) {
        const float t1r = wtot[w2][0], t1i = wtot[w2][1];
        const float t2r = wtot[w2][2], t2i = wtot[w2][3];
        const float nc1r = fmaf(Mr[6], c1r, fmaf(-Mi[6], c1i, t1r));
        const float nc1i = fmaf(Mr[6], c1i, fmaf( Mi[6], c1r, t1i));
        const float nc2r = fmaf(Mr[6], c2r, fmaf(-Mi[6], c2i, t2r));
        const float nc2i = fmaf(Mr[6], c2i, fmaf( Mi[6], c2r, t2i));
        c1r = nc1r; c1i = nc1i; c2r = nc2r; c2i = nc2i;
    }

    // exclusive in-wave prefix
    float p1r = __shfl_up(S1r, 1, 64);
    float p1i = __shfl_up(S1i, 1, 64);
    float p2r = __shfl_up(S2r, 1, 64);
    float p2i = __shfl_up(S2i, 1, 64);
    if (lane == 0) { p1r = p1i = p2r = p2i = 0.f; }

    // m^lane (product over set bits of lane)
    float plr = 1.f, pli = 0.f;
#pragma unroll
    for (int k = 0; k < 6; ++k) {
        if ((lane >> k) & 1) {
            const float nr2 = plr * Mr[k] - pli * Mi[k];
            const float ni2 = plr * Mi[k] + pli * Mr[k];
            plr = nr2; pli = ni2;
        }
    }
    // state entering this thread's segment
    z1r = fmaf(plr, c1r, fmaf(-pli, c1i, p1r));
    z1i = fmaf(plr, c1i, fmaf( pli, c1r, p1i));
    z2r = fmaf(plr, c2r, fmaf(-pli, c2i, p2r));
    z2i = fmaf(plr, c2i, fmaf( pli, c2r, p2i));

    // ---------------- phase B: re-scan with carries, direct store -----------
    const int nout = n0 + ((t - OUT_T0) << 4);
    if (t >= OUT_T0 && nout < N_SAMP) {
        LOAD_STREAMS();
        float* op = out + ((size_t)(b * NO + O)) * (size_t)N_SAMP + nout;
#pragma unroll
        for (int jq = 0; jq < 4; ++jq) {
            float4 yv;
#pragma unroll
            for (int u = 0; u < 4; ++u) {
                const int j = jq * 4 + u;
                const float n1r = fmaf(gr, z1r, fmaf(-gi_, z1i, sa[j]));
                const float n1i = fmaf(gi_, z1r, gr * z1i);
                z1r = n1r; z1i = n1i;
                const float n2r = fmaf(gr, z2r, fmaf(-gi_, z2i, sc[j]));
                const float n2i = fmaf(gi_, z2r, gr * z2i);
                z2r = n2r; z2i = n2i;
                const float y = z1i - fmaf(gWr, z2i, gWi * z2r);
                ((float*)&yv)[u] = y;
            }
            *(float4*)(op + jq * 4) = yv;
        }
    }
#undef LOAD_STREAMS
}

__global__ __launch_bounds__(NT, 6)
void duh_kernel(const float* __restrict__ x, const float* __restrict__ logw,
                float* __restrict__ out)
{
    extern __shared__ float lds_x[];
    __shared__ float wtot[8][4];
    const int cid = blockIdx.x;
    const int b   = blockIdx.y;
    if      (cid < 13) duh_run<0>(x, logw, out, lds_x, wtot, cid,      b);
    else if (cid < 24) duh_run<1>(x, logw, out, lds_x, wtot, cid - 13, b);
    else if (cid < 34) duh_run<2>(x, logw, out, lds_x, wtot, cid - 24, b);
    else if (cid < 44) duh_run<3>(x, logw, out, lds_x, wtot, cid - 34, b);
    else if (cid < 53) duh_run<4>(x, logw, out, lds_x, wtot, cid - 44, b);
    else if (cid < 62) duh_run<5>(x, logw, out, lds_x, wtot, cid - 53, b);
    else if (cid < 71) duh_run<6>(x, logw, out, lds_x, wtot, cid - 62, b);
    else               duh_run<7>(x, logw, out, lds_x, wtot, cid - 71, b);
}

extern "C" void kernel_launch(void* const* d_in, const int* in_sizes, int n_in,
                              void* d_out, int out_size, void* d_ws, size_t ws_size,
                              hipStream_t stream) {
    const float* x  = (const float*)d_in[0];
    const float* lw = (const float*)d_in[1];
    float* out = (float*)d_out;

    // dynamic LDS sized for the largest channel (O=0): XW = 8192+1856 = 10048
    // padded words = 10048 + 4*(10048/32) = 11304 -> 45216 bytes
    const size_t lds_bytes = (size_t)(10048 + 4 * (10048 / 32)) * sizeof(float);

    dim3 grid(80, NB);   // 80 chunk-slots x 16 batches = 1280 blocks
    duh_kernel<<<grid, dim3(NT), lds_bytes, stream>>>(x, lw, out);
}

// Round 4
// 25.689 us; speedup vs baseline: 1.5118x; 1.0253x over previous
//
#include <hip/hip_runtime.h>
#include <math.h>

// Duhamel layer == per-channel causal FIR with h[q] = (1/wD) r^q sin(q*theta).
// Single-complex-stream form: e[k] = xs[k] - g^W * xs[k-W]   (xs = x / wD)
//                             Z    = g*Z + e[k],   y[n] = Im(Z[n])
// (both truncation streams share pole g, so they fold into one recurrence).
// Chunked with per-channel compile-time halo; intra-block affine scan gives
// each thread its exact seed u; phase B is y[j] = ly[j] + Im(g^{j+1} u).

#define N_SAMP  65536
#define NB      16
#define NO      8
#define SPAN    8192
#define NT      512
#define LSEG    16

// Static FIR lengths (exact replica of reference VALID_W):
constexpr int CW[NO]  = {1844, 1317, 1024, 768, 576, 419, 307, 230};
// Halo: ceil(7/alpha) rounded to 32 (seed error e^-7 ~ 9e-4 relative).
constexpr int CHH[NO] = {2816, 2016, 1568, 1184, 896, 640, 480, 352};
// chunks = ceil(65536/(8192-H)) = {13,11,10,10,9,9,9,9}; prefix totals 80.

// +4 floats of pad per 32 (every 4-aligned logical idx stays 16B-aligned)
__device__ __forceinline__ int pidx4(int i) { return i + ((i >> 5) << 2); }

template<int O>
__device__ __forceinline__ void duh_run(const float* __restrict__ xg,
                                        const float* __restrict__ logw,
                                        float* __restrict__ out,
                                        float* __restrict__ lds_x,
                                        float (* __restrict__ wtot)[2],
                                        int c, int b)
{
    constexpr int W    = CW[O];
    constexpr int Wpad = (W + 31) & ~31;
    constexpr int H    = CHH[O];
    constexpr int L    = SPAN - H;
    constexpr int XW   = SPAN + Wpad;
    constexpr int OUT_T0 = H / LSEG;
    constexpr int E    = Wpad - W;           // 0..31 static
    constexpr int D    = E & 3;              // quad mis-shift, static
    constexpr int NQ2H = (D == 0) ? 2 : 3;   // stream-2 quads per 8 samples

    const int n0   = c * L;
    const int t    = threadIdx.x;
    const int lane = t & 63;
    const int wv   = t >> 6;

    // ---------------- per-channel constants (f32, from runtime logw) --------
    const float XIf = 0.05f, DTf = 0.01f;
    const float omf  = fminf(fmaxf(expf(logw[O]), 0.01f), 1000.0f);
    const float omD  = omf * sqrtf(1.0f - XIf * XIf);
    const float th   = omD * DTf;
    const float alph = XIf * omf * DTf;
    const float binv = 1.0f / omD;

    float sn, cn;
    const float r1 = expf(-alph);
    sincosf(th, &sn, &cn);
    const float gr = r1 * cn, gi = r1 * sn;             // g

    const float rW = expf(-alph * (float)W);
    sincosf(th * (float)W, &sn, &cn);
    const float gWr = rW * cn, gWi = rW * sn;           // g^W

    float Mr[7], Mi[7];                                  // M[k] = g^(16*2^k)
    {
        const float rl = expf(-alph * (float)LSEG);
        sincosf(th * (float)LSEG, &sn, &cn);
        float pr = rl * cn, pq = rl * sn;
#pragma unroll
        for (int k = 0; k < 7; ++k) {
            Mr[k] = pr; Mi[k] = pq;
            const float nr = pr * pr - pq * pq;
            const float ni = 2.0f * pr * pq;
            pr = nr; pq = ni;
        }
    }

    // ---------------- stage binv*x window into LDS (quad-padded) ------------
    const int xbase = n0 - H - Wpad;                     // global idx of lds_x[0]
    const float* xb = xg + (size_t)b * N_SAMP;
    for (int k = 4 * t; k < XW; k += 4 * NT) {
        const int g0 = xbase + k;
        float4 v;
        if (g0 >= 0 && g0 + 3 < N_SAMP) {
            v = *(const float4*)(xb + g0);
        } else {
            v.x = (g0 + 0 >= 0 && g0 + 0 < N_SAMP) ? xb[g0 + 0] : 0.0f;
            v.y = (g0 + 1 >= 0 && g0 + 1 < N_SAMP) ? xb[g0 + 1] : 0.0f;
            v.z = (g0 + 2 >= 0 && g0 + 2 < N_SAMP) ? xb[g0 + 2] : 0.0f;
            v.w = (g0 + 3 >= 0 && g0 + 3 < N_SAMP) ? xb[g0 + 3] : 0.0f;
        }
        v.x *= binv; v.y *= binv; v.z *= binv; v.w *= binv;
        *(float4*)&lds_x[pidx4(k)] = v;
    }
    __syncthreads();

    // ---------------- phase A: local scan of e-stream, zero seed ------------
    const int b1  = Wpad + (t << 4);     // mult of 16 -> 4 quads share 32-group
    const int pb1 = pidx4(b1);
    const int a2  = b1 - W - D;          // stream-2 aligned quad base (mult 4)

    float ly[LSEG];
    float Br = 0.f, Bi = 0.f;
#pragma unroll
    for (int h = 0; h < 2; ++h) {
        float s1[8];
#pragma unroll
        for (int m = 0; m < 2; ++m) {
            const float4 q = *(const float4*)&lds_x[pb1 + 4 * (2 * h + m)];
            s1[4*m+0] = q.x; s1[4*m+1] = q.y; s1[4*m+2] = q.z; s1[4*m+3] = q.w;
        }
        float s2[8];
#pragma unroll
        for (int mm = 0; mm < NQ2H; ++mm) {
            const int m = 2 * h + mm;
            const float4 q = *(const float4*)&lds_x[pidx4(a2 + 4 * m)];
#pragma unroll
            for (int u = 0; u < 4; ++u) {
                const int idx = 4 * m + u - D - 8 * h;
                if (idx >= 0 && idx < 8)
                    s2[idx] = (u == 0) ? q.x : (u == 1) ? q.y : (u == 2) ? q.z : q.w;
            }
        }
#pragma unroll
        for (int j = 0; j < 8; ++j) {
            const float er = fmaf(-gWr, s2[j], s1[j]);   // Re e[k]
            const float ei = -gWi * s2[j];               // Im e[k]
            const float nr = fmaf(gr, Br, fmaf(-gi, Bi, er));
            const float ni = fmaf(gi, Br, fmaf( gr, Bi, ei));
            Br = nr; Bi = ni;
            ly[8 * h + j] = Bi;
        }
    }

    // ---------------- wave-level inclusive affine scan (single stream) ------
    float Sr = Br, Si = Bi;
#pragma unroll
    for (int k = 0; k < 6; ++k) {
        const int d = 1 << k;
        const float ur = __shfl_up(Sr, d, 64);
        const float ui = __shfl_up(Si, d, 64);
        if (lane >= d) {
            const float nr = fmaf(Mr[k], ur, fmaf(-Mi[k], ui, Sr));
            const float ni = fmaf(Mr[k], ui, fmaf( Mi[k], ur, Si));
            Sr = nr; Si = ni;
        }
    }
    if (lane == 63) { wtot[wv][0] = Sr; wtot[wv][1] = Si; }
    __syncthreads();

    // cross-wave carry (multiplier g^1024 = M[6])
    float cr = 0.f, ci = 0.f;
    for (int w2 = 0; w2 < wv; ++w2) {
        const float tr = wtot[w2][0], ti = wtot[w2][1];
        const float nr = fmaf(Mr[6], cr, fmaf(-Mi[6], ci, tr));
        const float ni = fmaf(Mr[6], ci, fmaf( Mi[6], cr, ti));
        cr = nr; ci = ni;
    }

    // exclusive in-wave prefix
    float pr_ = __shfl_up(Sr, 1, 64);
    float pi_ = __shfl_up(Si, 1, 64);
    if (lane == 0) { pr_ = 0.f; pi_ = 0.f; }

    // m^lane (product over set bits of lane)
    float plr = 1.f, pli = 0.f;
#pragma unroll
    for (int k = 0; k < 6; ++k) {
        if ((lane >> k) & 1) {
            const float nr = plr * Mr[k] - pli * Mi[k];
            const float ni = plr * Mi[k] + pli * Mr[k];
            plr = nr; pli = ni;
        }
    }
    // exact seed entering this thread's segment: u = p + m^lane * carry
    const float ur_ = fmaf(plr, cr, fmaf(-pli, ci, pr_));
    const float ui_ = fmaf(plr, ci, fmaf( pli, cr, pi_));

    // ---------------- phase B: y[j] = ly[j] + Im(g^{j+1} u); direct store ---
    const int nout = n0 + ((t - OUT_T0) << 4);
    if (t >= OUT_T0 && nout < N_SAMP) {
        float vr = fmaf(gr, ur_, -gi * ui_);   // v = g*u
        float vi = fmaf(gi, ur_,  gr * ui_);
        float* op = out + ((size_t)(b * NO + O)) * (size_t)N_SAMP + nout;
#pragma unroll
        for (int jq = 0; jq < 4; ++jq) {
            float4 yv;
#pragma unroll
            for (int u = 0; u < 4; ++u) {
                ((float*)&yv)[u] = ly[4 * jq + u] + vi;
                const float nr = fmaf(gr, vr, -gi * vi);
                const float ni = fmaf(gi, vr,  gr * vi);
                vr = nr; vi = ni;
            }
            *(float4*)(op + 4 * jq) = yv;
        }
    }
}

__global__ __launch_bounds__(NT, 6)
void duh_kernel(const float* __restrict__ x, const float* __restrict__ logw,
                float* __restrict__ out)
{
    extern __shared__ float lds_x[];
    __shared__ float wtot[8][2];
    const int cid = blockIdx.x;
    const int b   = blockIdx.y;
    if      (cid < 13) duh_run<0>(x, logw, out, lds_x, wtot, cid,      b);
    else if (cid < 24) duh_run<1>(x, logw, out, lds_x, wtot, cid - 13, b);
    else if (cid < 34) duh_run<2>(x, logw, out, lds_x, wtot, cid - 24, b);
    else if (cid < 44) duh_run<3>(x, logw, out, lds_x, wtot, cid - 34, b);
    else if (cid < 53) duh_run<4>(x, logw, out, lds_x, wtot, cid - 44, b);
    else if (cid < 62) duh_run<5>(x, logw, out, lds_x, wtot, cid - 53, b);
    else if (cid < 71) duh_run<6>(x, logw, out, lds_x, wtot, cid - 62, b);
    else               duh_run<7>(x, logw, out, lds_x, wtot, cid - 71, b);
}

extern "C" void kernel_launch(void* const* d_in, const int* in_sizes, int n_in,
                              void* d_out, int out_size, void* d_ws, size_t ws_size,
                              hipStream_t stream) {
    const float* x  = (const float*)d_in[0];
    const float* lw = (const float*)d_in[1];
    float* out = (float*)d_out;

    // dynamic LDS sized for the largest channel (O=0): XW = 8192+1856 = 10048
    // padded words = 10048 + 4*(10048/32) = 11304 -> 45216 bytes
    const size_t lds_bytes = (size_t)(10048 + 4 * (10048 / 32)) * sizeof(float);

    dim3 grid(80, NB);   // 80 chunk-slots x 16 batches = 1280 blocks
    duh_kernel<<<grid, dim3(NT), lds_bytes, stream>>>(x, lw, out);
}

// Round 6
// 22.523 us; speedup vs baseline: 1.7243x; 1.1406x over previous
//
#include <hip/hip_runtime.h>
#include <math.h>

// Duhamel layer == per-channel causal FIR with h[q] = (1/wD) r^q sin(q*theta).
// Single-stream form: e[k] = (x[k] - g^W x[k-W])/wD;  Z = g*Z + e[k];
// y[n] = Im(Z[n]).  No LDS staging: each thread loads its own x[k], x[k-W]
// quads from global (L2/L3-resident), runs the IIR, parks local y in LDS,
// fixes seeds via wave affine scan, RMWs LDS, then coalesced cooperative store.

#define N_SAMP  65536
#define NB      16
#define NO      8
#define SPAN    8192
#define NT      512
#define LSEG    16

// Static FIR lengths (exact replica of reference VALID_W):
constexpr int CW[NO]  = {1844, 1317, 1024, 768, 576, 419, 307, 230};
// Halo: ceil(7/alpha) rounded to 32 (seed error e^-7 ~ 9e-4 relative).
constexpr int CHH[NO] = {2816, 2016, 1568, 1184, 896, 640, 480, 352};
// chunks = ceil(65536/(8192-H)) = {13,11,10,10,9,9,9,9}; prefix totals 80.

#define LDSY  (SPAN + ((SPAN) >> 5) * 4)   // 9216 floats = 36,864 B

// +4 floats of pad per 32: thread-stride-64B b128 access covers all 32 banks
__device__ __forceinline__ int pidx4(int i) { return i + ((i >> 5) << 2); }

__device__ __forceinline__ float rfl(float x) {
    return __int_as_float(__builtin_amdgcn_readfirstlane(__float_as_int(x)));
}

template<int O>
__device__ __forceinline__ void duh_run(const float* __restrict__ xg,
                                        const float* __restrict__ logw,
                                        float* __restrict__ out,
                                        float* __restrict__ lds_y,
                                        float (* __restrict__ wtot)[2],
                                        int c, int b)
{
    constexpr int W    = CW[O];
    constexpr int H    = CHH[O];
    constexpr int L    = SPAN - H;
    constexpr int OUT_T0 = H / LSEG;
    // Aligned-quad shift for the delayed stream: (s1g - W - D) % 4 == 0.
    // s1g is a multiple of 16, so D = (-W) mod 4.  (r5 bug: used W&3 -> OOB.)
    constexpr int D    = (4 - (W & 3)) & 3;
    constexpr int NQH  = (D == 0) ? 2 : 3;   // delayed-stream quads per 8 samples

    const int n0   = c * L;
    const int t    = threadIdx.x;
    const int lane = t & 63;
    const int wv   = t >> 6;

    // ---------------- per-channel constants -> SGPR via readfirstlane -------
    const float XIf = 0.05f, DTf = 0.01f;
    const float omf  = fminf(fmaxf(expf(logw[O]), 0.01f), 1000.0f);
    const float omD  = omf * sqrtf(1.0f - XIf * XIf);
    const float th   = omD * DTf;
    const float alph = XIf * omf * DTf;

    float sn, cn;
    const float r1 = expf(-alph);
    sincosf(th, &sn, &cn);
    const float gr = rfl(r1 * cn), gi = rfl(r1 * sn);        // g

    const float rW = expf(-alph * (float)W);
    sincosf(th * (float)W, &sn, &cn);
    const float binv = rfl(1.0f / omD);
    const float sWr  = rfl(rW * cn);                         // Re g^W
    const float cei  = rfl(-binv * rW * sn);                 // -Im(g^W)/wD

    float Mr[7], Mi[7];                                       // M[k]=g^(16*2^k)
    {
        const float rl = expf(-alph * (float)LSEG);
        sincosf(th * (float)LSEG, &sn, &cn);
        float pr = rl * cn, pq = rl * sn;
#pragma unroll
        for (int k = 0; k < 7; ++k) {
            Mr[k] = rfl(pr); Mi[k] = rfl(pq);
            const float nr = pr * pr - pq * pq;
            const float ni = 2.0f * pr * pq;
            pr = nr; pq = ni;
        }
    }

    // ---------------- phase A: per-thread global loads + IIR, y -> LDS ------
    const float* xb = xg + (size_t)b * N_SAMP;
    const int s1g = (n0 - H) + (t << 4);      // stream-1 base (mult of 16)
    const int s2g = s1g - W - D;              // delayed-stream base (mult of 4)
    const int kb  = pidx4(t << 4);            // this thread's LDS base

    float Br = 0.f, Bi = 0.f;
#pragma unroll
    for (int h = 0; h < 2; ++h) {
        float s1[8];
#pragma unroll
        for (int m = 0; m < 2; ++m) {
            const int g = s1g + 4 * (2 * h + m);
            float4 q;
            if (g >= 0 && g < N_SAMP) {       // g mult of 4 -> whole quad ok
                q = *(const float4*)(xb + g);
            } else {
                q.x = (g + 0 >= 0 && g + 0 < N_SAMP) ? xb[g + 0] : 0.0f;
                q.y = (g + 1 >= 0 && g + 1 < N_SAMP) ? xb[g + 1] : 0.0f;
                q.z = (g + 2 >= 0 && g + 2 < N_SAMP) ? xb[g + 2] : 0.0f;
                q.w = (g + 3 >= 0 && g + 3 < N_SAMP) ? xb[g + 3] : 0.0f;
            }
            s1[4*m+0] = q.x; s1[4*m+1] = q.y; s1[4*m+2] = q.z; s1[4*m+3] = q.w;
        }
        float s2[8];
#pragma unroll
        for (int mm = 0; mm < NQH; ++mm) {
            const int m = 2 * h + mm;
            const int g = s2g + 4 * m;        // mult of 4
            float4 q;
            if (g >= 0 && g < N_SAMP) {
                q = *(const float4*)(xb + g);
            } else {
                q.x = (g + 0 >= 0 && g + 0 < N_SAMP) ? xb[g + 0] : 0.0f;
                q.y = (g + 1 >= 0 && g + 1 < N_SAMP) ? xb[g + 1] : 0.0f;
                q.z = (g + 2 >= 0 && g + 2 < N_SAMP) ? xb[g + 2] : 0.0f;
                q.w = (g + 3 >= 0 && g + 3 < N_SAMP) ? xb[g + 3] : 0.0f;
            }
#pragma unroll
            for (int u = 0; u < 4; ++u) {
                const int idx = 4 * m + u - D - 8 * h;
                if (idx >= 0 && idx < 8)
                    s2[idx] = (u == 0) ? q.x : (u == 1) ? q.y : (u == 2) ? q.z : q.w;
            }
        }
#pragma unroll
        for (int m = 0; m < 2; ++m) {
            float4 yq;
#pragma unroll
            for (int u = 0; u < 4; ++u) {
                const int j = 4 * m + u;
                const float a  = s1[j];
                const float cc = s2[j];
                const float tt = fmaf(-sWr, cc, a);
                const float er = binv * tt;                 // Re e
                const float ei = cei * cc;                  // Im e
                const float nr = fmaf(gr, Br, fmaf(-gi, Bi, er));
                const float ni = fmaf(gi, Br, fmaf( gr, Bi, ei));
                Br = nr; Bi = ni;
                ((float*)&yq)[u] = Bi;
            }
            *(float4*)&lds_y[kb + 8 * h + 4 * m] = yq;
        }
    }

    // ---------------- wave-level inclusive affine scan ----------------------
    float Sr = Br, Si = Bi;
#pragma unroll
    for (int k = 0; k < 6; ++k) {
        const int d = 1 << k;
        const float ur = __shfl_up(Sr, d, 64);
        const float ui = __shfl_up(Si, d, 64);
        if (lane >= d) {
            const float nr = fmaf(Mr[k], ur, fmaf(-Mi[k], ui, Sr));
            const float ni = fmaf(Mr[k], ui, fmaf( Mi[k], ur, Si));
            Sr = nr; Si = ni;
        }
    }
    if (lane == 63) { wtot[wv][0] = Sr; wtot[wv][1] = Si; }
    __syncthreads();

    // cross-wave carry (multiplier g^1024 = M[6])
    float cr = 0.f, ci = 0.f;
    for (int w2 = 0; w2 < wv; ++w2) {
        const float tr = wtot[w2][0], ti = wtot[w2][1];
        const float nr = fmaf(Mr[6], cr, fmaf(-Mi[6], ci, tr));
        const float ni = fmaf(Mr[6], ci, fmaf( Mi[6], cr, ti));
        cr = nr; ci = ni;
    }

    // exclusive in-wave prefix
    float pr_ = __shfl_up(Sr, 1, 64);
    float pi_ = __shfl_up(Si, 1, 64);
    if (lane == 0) { pr_ = 0.f; pi_ = 0.f; }

    // m^lane (product over set bits of lane)
    float plr = 1.f, pli = 0.f;
#pragma unroll
    for (int k = 0; k < 6; ++k) {
        if ((lane >> k) & 1) {
            const float nr = plr * Mr[k] - pli * Mi[k];
            const float ni = plr * Mi[k] + pli * Mr[k];
            plr = nr; pli = ni;
        }
    }
    // seed entering this thread's segment: u = p + m^lane * carry
    const float ur_ = fmaf(plr, cr, fmaf(-pli, ci, pr_));
    const float ui_ = fmaf(plr, ci, fmaf( pli, cr, pi_));

    // ---------------- phase B: in-place LDS RMW with rotation correction ----
    if (t >= OUT_T0) {
        float vr = fmaf(gr, ur_, -(gi * ui_));   // v = g*u
        float vi = fmaf(gi, ur_,  (gr * ui_));
#pragma unroll
        for (int m = 0; m < 4; ++m) {
            float4 yq = *(float4*)&lds_y[kb + 4 * m];
#pragma unroll
            for (int u = 0; u < 4; ++u) {
                ((float*)&yq)[u] += vi;
                const float nr = fmaf(gr, vr, -(gi * vi));
                const float ni = fmaf(gi, vr,  (gr * vi));
                vr = nr; vi = ni;
            }
            *(float4*)&lds_y[kb + 4 * m] = yq;
        }
    }
    __syncthreads();

    // ---------------- coalesced cooperative store ---------------------------
    const int kmax = (n0 + L <= N_SAMP) ? L : (N_SAMP - n0);
    float* op = out + ((size_t)(b * NO + O)) * (size_t)N_SAMP + n0;
    for (int k = 4 * t; k < kmax; k += 4 * NT) {
        const float4 v = *(const float4*)&lds_y[pidx4(H + k)];
        *(float4*)(op + k) = v;
    }
}

__global__ __launch_bounds__(NT, 8)
void duh_kernel(const float* __restrict__ x, const float* __restrict__ logw,
                float* __restrict__ out)
{
    __shared__ float lds_y[LDSY];
    __shared__ float wtot[8][2];
    const int cid = blockIdx.x;
    const int b   = blockIdx.y;
    if      (cid < 13) duh_run<0>(x, logw, out, lds_y, wtot, cid,      b);
    else if (cid < 24) duh_run<1>(x, logw, out, lds_y, wtot, cid - 13, b);
    else if (cid < 34) duh_run<2>(x, logw, out, lds_y, wtot, cid - 24, b);
    else if (cid < 44) duh_run<3>(x, logw, out, lds_y, wtot, cid - 34, b);
    else if (cid < 53) duh_run<4>(x, logw, out, lds_y, wtot, cid - 44, b);
    else if (cid < 62) duh_run<5>(x, logw, out, lds_y, wtot, cid - 53, b);
    else if (cid < 71) duh_run<6>(x, logw, out, lds_y, wtot, cid - 62, b);
    else               duh_run<7>(x, logw, out, lds_y, wtot, cid - 71, b);
}

extern "C" void kernel_launch(void* const* d_in, const int* in_sizes, int n_in,
                              void* d_out, int out_size, void* d_ws, size_t ws_size,
                              hipStream_t stream) {
    const float* x  = (const float*)d_in[0];
    const float* lw = (const float*)d_in[1];
    float* out = (float*)d_out;

    dim3 grid(80, NB);   // 80 chunk-slots x 16 batches = 1280 blocks
    duh_kernel<<<grid, dim3(NT), 0, stream>>>(x, lw, out);
}